// Round 3
// baseline (6002.643 us; speedup 1.0000x reference)
//
#include <hip/hip_runtime.h>

#define NNODE 50000
#define NEDGE 800000
#define NLAYER 4
#define BN_EPS 1e-5f

#define NH (NNODE*64)   // 3,200,000
#define NE (NEDGE*64)   // 51,200,000

typedef __attribute__((ext_vector_type(8))) short short8v;

__device__ __forceinline__ float sigf(float x){ return 1.0f/(1.0f+__expf(-x)); }

__device__ __forceinline__ float bf2f(unsigned short u){
  union { unsigned int i; float f; } c; c.i = ((unsigned int)u)<<16; return c.f;
}
__device__ __forceinline__ unsigned short f2bf(float f){
  union { float f; unsigned int i; } c; c.f = f;
  unsigned int r = c.i + 0x7FFFu + ((c.i>>16)&1u);   // RNE (finite values)
  return (unsigned short)(r>>16);
}

// ---------------------------------------------------------------- utility
__global__ void k_zero_i(int* __restrict__ p, int n){
  int i = blockIdx.x*256 + threadIdx.x;
  if(i<n) p[i]=0;
}
__global__ void k_zero_stats(float* __restrict__ stats){
  stats[threadIdx.x] = 0.f;   // one block of 256
}
__global__ void k_count(const int* __restrict__ ei, int* __restrict__ cnt){
  int i = blockIdx.x*256 + threadIdx.x;
  if(i<NEDGE) atomicAdd(&cnt[ei[i]], 1);   // ei[0][i] = dst
}
__global__ void k_inv(const int* __restrict__ cnt, float* __restrict__ invc){
  int i = blockIdx.x*256 + threadIdx.x;
  if(i<NNODE){ int c=cnt[i]; invc[i] = 1.0f/(float)(c<1?1:c); }
}

__global__ void k_init_h(const float* __restrict__ x, const float* __restrict__ w,
                         const float* __restrict__ b, float* __restrict__ h){
  int t = blockIdx.x*256 + threadIdx.x;
  if(t>=NH) return;
  int i=t>>6, j=t&63;
  float v = x[2*i]*w[j] + x[2*i+1]*w[64+j] + b[j];
  h[t] = fmaxf(v, 0.0f);
}

__global__ void k_init_e(const float* __restrict__ ea, const float* __restrict__ w,
                         const float* __restrict__ b, unsigned short* __restrict__ e){
  int t = blockIdx.x*256 + threadIdx.x;      // pair index
  if(t >= NE/2) return;
  int i = t>>5;          // (2t)>>6
  int j = (t&31)<<1;     // (2t)&63
  float a = ea[i];
  float v0 = fmaxf(a*w[j]   + b[j],   0.f);
  float v1 = fmaxf(a*w[j+1] + b[j+1], 0.f);
  unsigned int pk = (unsigned int)f2bf(v0) | ((unsigned int)f2bf(v1)<<16);
  *reinterpret_cast<unsigned int*>(&e[2*t]) = pk;
}

// ------------------------------------------------------------ tile helpers
// At[k][row] = A[row][k] (transposed), Ws[k][col]; 4x4 micro-tile per thread.
__device__ __forceinline__ void tile_gemm(const float (&At)[64][68], const float (&Ws)[64][68],
                                          int r0, int c0, float (&acc)[4][4]){
  #pragma unroll 4
  for(int k=0;k<64;++k){
    const float4 a = *reinterpret_cast<const float4*>(&At[k][r0]);
    const float4 b = *reinterpret_cast<const float4*>(&Ws[k][c0]);
    const float av[4]={a.x,a.y,a.z,a.w};
    const float bv[4]={b.x,b.y,b.z,b.w};
    #pragma unroll
    for(int ri=0;ri<4;++ri)
      #pragma unroll
      for(int ci=0;ci<4;++ci)
        acc[ri][ci] = fmaf(av[ri], bv[ci], acc[ri][ci]);
  }
}

// fp32 source tile (node features), transposed into At; rows guarded
__device__ __forceinline__ void stage_At_f32(float (&At)[64][68], const float* __restrict__ src,
                                             int row0, int rowmax, int tid){
  for(int it=0; it<4; ++it){
    int idx = tid + it*256;
    int r = idx>>4, c4=(idx&15)<<2;
    int gr = row0 + r;
    float4 v = make_float4(0.f,0.f,0.f,0.f);
    if(gr < rowmax) v = *reinterpret_cast<const float4*>(&src[(size_t)gr*64 + c4]);
    At[c4+0][r]=v.x; At[c4+1][r]=v.y; At[c4+2][r]=v.z; At[c4+3][r]=v.w;
  }
}

// bf16 source tile (edge features e); NEDGE%64==0 so no row guard
__device__ __forceinline__ void stage_At_bf16(float (&At)[64][68], const unsigned short* __restrict__ src,
                                              int row0, int tid){
  #pragma unroll
  for(int it=0; it<2; ++it){
    int idx = tid + it*256;          // 0..511
    int r = idx>>3, c8 = (idx&7)<<3;
    int gr = row0 + r;
    const short8v v = *reinterpret_cast<const short8v*>(&src[(size_t)gr*64 + c8]);
    #pragma unroll
    for(int j=0;j<8;++j) At[c8+j][r] = bf2f((unsigned short)v[j]);
  }
}

__device__ __forceinline__ void stage_W(float (&Ws)[64][68], const float* __restrict__ W, int tid){
  for(int it=0; it<4; ++it){
    int idx = tid + it*256;
    int k = idx>>4, c4=(idx&15)<<2;
    *reinterpret_cast<float4*>(&Ws[k][c4]) = *reinterpret_cast<const float4*>(&W[k*64+c4]);
  }
}

// ---------------------------------------------------------- node GEMMs (U,V,B,C)
__device__ __forceinline__ void node_one_mat(float (&At)[64][68], float (&Ws)[64][68],
    const float* __restrict__ W, const float* __restrict__ B, float* __restrict__ O,
    int row0, int tid){
  __syncthreads();
  stage_W(Ws, W, tid);
  __syncthreads();
  const int tx=tid&15, ty=tid>>4, r0=tx<<2, c0=ty<<2;
  float acc[4][4]={{0.f}};
  tile_gemm(At, Ws, r0, c0, acc);
  const float4 b4 = *reinterpret_cast<const float4*>(&B[c0]);
  const float bb[4]={b4.x,b4.y,b4.z,b4.w};
  #pragma unroll
  for(int ri=0;ri<4;++ri){
    int gr = row0 + r0 + ri;
    if(gr < NNODE){
      float4 o = make_float4(acc[ri][0]+bb[0], acc[ri][1]+bb[1],
                             acc[ri][2]+bb[2], acc[ri][3]+bb[3]);
      *reinterpret_cast<float4*>(&O[(size_t)gr*64 + c0]) = o;
    }
  }
}

__global__ __launch_bounds__(256) void k_node_gemm(
    const float* __restrict__ h,
    const float* __restrict__ Uw, const float* __restrict__ Ub,
    const float* __restrict__ Vw, const float* __restrict__ Vb,
    const float* __restrict__ Bw, const float* __restrict__ Bb,
    const float* __restrict__ Cw, const float* __restrict__ Cb,
    float* __restrict__ Uh, float* __restrict__ Vh,
    float* __restrict__ Bh, float* __restrict__ Ch)
{
  __shared__ float At[64][68];
  __shared__ float Ws[64][68];
  const int tid = threadIdx.x;
  const int row0 = blockIdx.x*64;
  stage_At_f32(At, h, row0, NNODE, tid);
  node_one_mat(At, Ws, Uw, Ub, Uh, row0, tid);
  node_one_mat(At, Ws, Vw, Vb, Vh, row0, tid);
  node_one_mat(At, Ws, Bw, Bb, Bh, row0, tid);
  node_one_mat(At, Ws, Cw, Cb, Ch, row0, tid);
}

// ---------------------------------------------------------- edge pass A
// t = e@Aw + Ab + Bh[dst] + Ch[src]; accumulate e-BN stats of t.
// also: Uh[dst] += sigmoid(e_in) * Vh[src] * invc[dst]   (pre-divided mean)
__global__ __launch_bounds__(256) void k_edge_A(
    const unsigned short* __restrict__ e,
    const float* __restrict__ Aw, const float* __restrict__ Ab,
    const float* __restrict__ Bh, const float* __restrict__ Ch,
    const float* __restrict__ Vh,
    const int* __restrict__ ei, const float* __restrict__ invc,
    float* __restrict__ Uh, float* __restrict__ stats)
{
  __shared__ float At[64][68];
  __shared__ float Ws[64][68];
  __shared__ float red[128];
  const int tid=threadIdx.x;
  const int row0 = blockIdx.x*64;
  if(tid<128) red[tid]=0.f;
  stage_At_bf16(At, e, row0, tid);
  stage_W(Ws, Aw, tid);
  __syncthreads();
  const int tx=tid&15, ty=tid>>4, r0=tx<<2, c0=ty<<2;
  float acc[4][4]={{0.f}};
  tile_gemm(At, Ws, r0, c0, acc);

  int dstI[4], srcI[4];
  float ic[4];
  #pragma unroll
  for(int ri=0;ri<4;++ri){
    dstI[ri]=ei[row0+r0+ri];
    srcI[ri]=ei[NEDGE+row0+r0+ri];
    ic[ri]=invc[dstI[ri]];
  }
  const float4 ab4 = *reinterpret_cast<const float4*>(&Ab[c0]);
  const float ab[4]={ab4.x,ab4.y,ab4.z,ab4.w};

  float ein[4][4];
  #pragma unroll
  for(int ci=0;ci<4;++ci){
    const float4 q = *reinterpret_cast<const float4*>(&At[c0+ci][r0]);
    ein[0][ci]=q.x; ein[1][ci]=q.y; ein[2][ci]=q.z; ein[3][ci]=q.w;
  }

  float s1[4]={0.f,0.f,0.f,0.f}, s2[4]={0.f,0.f,0.f,0.f};
  #pragma unroll
  for(int ri=0;ri<4;++ri){
    const float4 bh4 = *reinterpret_cast<const float4*>(&Bh[(size_t)dstI[ri]*64 + c0]);
    const float4 ch4 = *reinterpret_cast<const float4*>(&Ch[(size_t)srcI[ri]*64 + c0]);
    const float4 vh4 = *reinterpret_cast<const float4*>(&Vh[(size_t)srcI[ri]*64 + c0]);
    const float bh[4]={bh4.x,bh4.y,bh4.z,bh4.w};
    const float ch[4]={ch4.x,ch4.y,ch4.z,ch4.w};
    const float vh[4]={vh4.x,vh4.y,vh4.z,vh4.w};
    #pragma unroll
    for(int ci=0;ci<4;++ci){
      float t = acc[ri][ci] + ab[ci] + bh[ci] + ch[ci];
      s1[ci]+=t; s2[ci]+=t*t;
      float g = sigf(ein[ri][ci]);
      atomicAdd(&Uh[(size_t)dstI[ri]*64 + c0 + ci], g*vh[ci]*ic[ri]);
    }
  }
  #pragma unroll
  for(int ci=0;ci<4;++ci){
    atomicAdd(&red[c0+ci],    s1[ci]);
    atomicAdd(&red[64+c0+ci], s2[ci]);
  }
  __syncthreads();
  if(tid<64){
    atomicAdd(&stats[tid],    red[tid]);
    atomicAdd(&stats[64+tid], red[64+tid]);
  }
}

// ---------------------------------------------------------- node finalize
// Uh already holds Uh + mean-agg. Accumulate h BN stats.
__global__ void k_node_finA(const float* __restrict__ Uh, float* __restrict__ stats){
  __shared__ float red[128];
  const int tid=threadIdx.x;
  if(tid<128) red[tid]=0.f;
  __syncthreads();
  int t = blockIdx.x*256 + tid;   // NH % 256 == 0
  int j=t&63;
  float v = Uh[t];
  atomicAdd(&red[j], v);
  atomicAdd(&red[64+j], v*v);
  __syncthreads();
  if(tid<64){
    atomicAdd(&stats[128+tid], red[tid]);
    atomicAdd(&stats[192+tid], red[64+tid]);
  }
}

__global__ void k_node_finB(const float* __restrict__ th, float* __restrict__ h,
                            const float* __restrict__ stats,
                            const float* __restrict__ hg, const float* __restrict__ hb){
  int t = blockIdx.x*256 + threadIdx.x;
  if(t>=NH) return;
  int j=t&63;
  const float invN = 1.0f/(float)NNODE;
  float mean = stats[128+j]*invN;
  float var  = stats[192+j]*invN - mean*mean;
  float rstd = rsqrtf(var + BN_EPS);
  float v = (th[t]-mean)*rstd*hg[j] + hb[j];
  h[t] += fmaxf(v, 0.0f);
}

// ---------------------------------------------------------- edge pass B
// recompute t, normalize with e-stats, e = e_in + relu(bn(t))  (in place, bf16)
__global__ __launch_bounds__(256) void k_edge_B(
    unsigned short* __restrict__ e,
    const float* __restrict__ Aw, const float* __restrict__ Ab,
    const float* __restrict__ Bh, const float* __restrict__ Ch,
    const int* __restrict__ ei,
    const float* __restrict__ stats,
    const float* __restrict__ eg, const float* __restrict__ eb)
{
  __shared__ float At[64][68];
  __shared__ float Ws[64][68];
  const int tid=threadIdx.x;
  const int row0 = blockIdx.x*64;
  stage_At_bf16(At, e, row0, tid);
  stage_W(Ws, Aw, tid);
  __syncthreads();
  const int tx=tid&15, ty=tid>>4, r0=tx<<2, c0=ty<<2;
  float acc[4][4]={{0.f}};
  tile_gemm(At, Ws, r0, c0, acc);

  int dstI[4], srcI[4];
  #pragma unroll
  for(int ri=0;ri<4;++ri){
    dstI[ri]=ei[row0+r0+ri];
    srcI[ri]=ei[NEDGE+row0+r0+ri];
  }
  const float4 ab4 = *reinterpret_cast<const float4*>(&Ab[c0]);
  const float ab[4]={ab4.x,ab4.y,ab4.z,ab4.w};
  const float invE = 1.0f/(float)NEDGE;
  const float4 s14 = *reinterpret_cast<const float4*>(&stats[c0]);
  const float4 s24 = *reinterpret_cast<const float4*>(&stats[64+c0]);
  const float4 gg4 = *reinterpret_cast<const float4*>(&eg[c0]);
  const float4 bb4 = *reinterpret_cast<const float4*>(&eb[c0]);
  float mean[4], rstd[4], gg[4], bb[4];
  {
    const float s1v[4]={s14.x,s14.y,s14.z,s14.w};
    const float s2v[4]={s24.x,s24.y,s24.z,s24.w};
    const float ggv[4]={gg4.x,gg4.y,gg4.z,gg4.w};
    const float bbv[4]={bb4.x,bb4.y,bb4.z,bb4.w};
    #pragma unroll
    for(int ci=0;ci<4;++ci){
      mean[ci]=s1v[ci]*invE;
      float var = s2v[ci]*invE - mean[ci]*mean[ci];
      rstd[ci]=rsqrtf(var+BN_EPS);
      gg[ci]=ggv[ci]; bb[ci]=bbv[ci];
    }
  }
  float ein[4][4];
  #pragma unroll
  for(int ci=0;ci<4;++ci){
    const float4 q = *reinterpret_cast<const float4*>(&At[c0+ci][r0]);
    ein[0][ci]=q.x; ein[1][ci]=q.y; ein[2][ci]=q.z; ein[3][ci]=q.w;
  }
  #pragma unroll
  for(int ri=0;ri<4;++ri){
    const float4 bh4 = *reinterpret_cast<const float4*>(&Bh[(size_t)dstI[ri]*64 + c0]);
    const float4 ch4 = *reinterpret_cast<const float4*>(&Ch[(size_t)srcI[ri]*64 + c0]);
    const float bh[4]={bh4.x,bh4.y,bh4.z,bh4.w};
    const float ch[4]={ch4.x,ch4.y,ch4.z,ch4.w};
    unsigned int pk[2];
    #pragma unroll
    for(int p=0;p<2;++p){
      float o0, o1;
      {
        int ci=2*p;
        float t = acc[ri][ci] + ab[ci] + bh[ci] + ch[ci];
        float v = (t-mean[ci])*rstd[ci]*gg[ci] + bb[ci];
        o0 = ein[ri][ci] + fmaxf(v, 0.0f);
        ci=2*p+1;
        t = acc[ri][ci] + ab[ci] + bh[ci] + ch[ci];
        v = (t-mean[ci])*rstd[ci]*gg[ci] + bb[ci];
        o1 = ein[ri][ci] + fmaxf(v, 0.0f);
      }
      pk[p] = (unsigned int)f2bf(o0) | ((unsigned int)f2bf(o1)<<16);
    }
    *reinterpret_cast<uint2*>(&e[(size_t)(row0+r0+ri)*64 + c0]) = make_uint2(pk[0], pk[1]);
  }
}

// ---------------------------------------------------------- final MLP (fused)
__global__ __launch_bounds__(256) void k_mlp(
    const unsigned short* __restrict__ e,
    const float* __restrict__ f1w, const float* __restrict__ f1b,
    const float* __restrict__ f2w, const float* __restrict__ f2b,
    const float* __restrict__ f3w, const float* __restrict__ f3b,
    float* __restrict__ out)
{
  __shared__ float At[64][68];
  __shared__ float Ws[64][68];
  __shared__ float ored[64];
  const int tid=threadIdx.x;
  const int row0 = blockIdx.x*64;
  if(tid<64) ored[tid]=0.f;
  stage_At_bf16(At, e, row0, tid);
  stage_W(Ws, f1w, tid);
  __syncthreads();
  const int tx=tid&15, ty=tid>>4, r0=tx<<2, c0=ty<<2;
  float acc[4][4]={{0.f}};
  tile_gemm(At, Ws, r0, c0, acc);
  const float4 b14 = *reinterpret_cast<const float4*>(&f1b[c0]);
  const float b1[4]={b14.x,b14.y,b14.z,b14.w};
  float z1[4][4];
  #pragma unroll
  for(int ri=0;ri<4;++ri)
    #pragma unroll
    for(int ci=0;ci<4;++ci){
      float v = acc[ri][ci]+b1[ci];
      z1[ri][ci] = v*sigf(v);
    }
  __syncthreads();                 // everyone done reading At/Ws
  #pragma unroll
  for(int ri=0;ri<4;++ri)
    #pragma unroll
    for(int ci=0;ci<4;++ci)
      At[c0+ci][r0+ri] = z1[ri][ci];   // z1 transposed
  stage_W(Ws, f2w, tid);
  __syncthreads();
  float acc2[4][4]={{0.f}};
  tile_gemm(At, Ws, r0, c0, acc2);
  const float4 b24 = *reinterpret_cast<const float4*>(&f2b[c0]);
  const float b2[4]={b24.x,b24.y,b24.z,b24.w};
  const float4 w34 = *reinterpret_cast<const float4*>(&f3w[c0]);
  const float w3[4]={w34.x,w34.y,w34.z,w34.w};
  float part[4]={0.f,0.f,0.f,0.f};
  #pragma unroll
  for(int ri=0;ri<4;++ri)
    #pragma unroll
    for(int ci=0;ci<4;++ci){
      float v = acc2[ri][ci]+b2[ci];
      float z = v*sigf(v);
      part[ri] += z*w3[ci];
    }
  #pragma unroll
  for(int ri=0;ri<4;++ri) atomicAdd(&ored[r0+ri], part[ri]);
  __syncthreads();
  if(tid<64) out[row0+tid] = sigf(ored[tid] + f3b[0]);
}

// ---------------------------------------------------------------- launch
extern "C" void kernel_launch(void* const* d_in, const int* in_sizes, int n_in,
                              void* d_out, int out_size, void* d_ws, size_t ws_size,
                              hipStream_t stream){
  const float* x    = (const float*)d_in[0];
  const float* ea   = (const float*)d_in[1];
  const int*   ei   = (const int*)  d_in[2];
  const float* hp_w = (const float*)d_in[3];
  const float* hp_b = (const float*)d_in[4];
  const float* ep_w = (const float*)d_in[5];
  const float* ep_b = (const float*)d_in[6];
  const float* Uw   = (const float*)d_in[7];
  const float* Ub   = (const float*)d_in[8];
  const float* Vw   = (const float*)d_in[9];
  const float* Vb   = (const float*)d_in[10];
  const float* Aw   = (const float*)d_in[11];
  const float* Ab   = (const float*)d_in[12];
  const float* Bw   = (const float*)d_in[13];
  const float* Bb   = (const float*)d_in[14];
  const float* Cw   = (const float*)d_in[15];
  const float* Cb   = (const float*)d_in[16];
  const float* hg   = (const float*)d_in[17];
  const float* hb   = (const float*)d_in[18];
  const float* eg   = (const float*)d_in[19];
  const float* eb   = (const float*)d_in[20];
  const float* f1w  = (const float*)d_in[21];
  const float* f1b  = (const float*)d_in[22];
  const float* f2w  = (const float*)d_in[23];
  const float* f2b  = (const float*)d_in[24];
  const float* f3w  = (const float*)d_in[25];
  const float* f3b  = (const float*)d_in[26];

  // workspace layout (bytes): e(bf16, NE) | h | Uh | Vh | Bh | Ch | stats | cnt | invc
  char* base = (char*)d_ws;
  unsigned short* e = (unsigned short*)base;              // 102,400,000 B (16B-aligned end)
  float* h     = (float*)(base + (size_t)NE*2);
  float* Uh    = h  + (size_t)NH;
  float* Vh    = h  + 2ull*NH;
  float* Bh    = h  + 3ull*NH;
  float* Ch    = h  + 4ull*NH;
  float* stats = h  + 5ull*NH;          // 256 floats
  int*   cnt   = (int*)(stats + 256);   // 50176 ints
  float* invc  = (float*)(cnt + 50176); // 50176 floats
  // total ≈ 167.2 MB

  dim3 blk(256);
  k_zero_i<<<dim3(196), blk, 0, stream>>>(cnt, 50176);
  k_count <<<dim3((NEDGE+255)/256), blk, 0, stream>>>(ei, cnt);
  k_inv   <<<dim3((NNODE+255)/256), blk, 0, stream>>>(cnt, invc);
  k_init_h<<<dim3((NH+255)/256), blk, 0, stream>>>(x, hp_w, hp_b, h);
  k_init_e<<<dim3((NE/2+255)/256), blk, 0, stream>>>(ea, ep_w, ep_b, e);

  for(int l=0;l<NLAYER;++l){
    k_zero_stats<<<dim3(1), blk, 0, stream>>>(stats);
    k_node_gemm<<<dim3((NNODE+63)/64), blk, 0, stream>>>(h,
        Uw+l*4096, Ub+l*64, Vw+l*4096, Vb+l*64,
        Bw+l*4096, Bb+l*64, Cw+l*4096, Cb+l*64,
        Uh, Vh, Bh, Ch);
    k_edge_A<<<dim3(NEDGE/64), blk, 0, stream>>>(e, Aw+l*4096, Ab+l*64,
        Bh, Ch, Vh, ei, invc, Uh, stats);
    k_node_finA<<<dim3(NH/256), blk, 0, stream>>>(Uh, stats);
    k_node_finB<<<dim3(NH/256), blk, 0, stream>>>(Uh, h, stats, hg+l*64, hb+l*64);
    k_edge_B<<<dim3(NEDGE/64), blk, 0, stream>>>(e, Aw+l*4096, Ab+l*64,
        Bh, Ch, ei, stats, eg+l*64, eb+l*64);
  }
  k_mlp<<<dim3(NEDGE/64), blk, 0, stream>>>(e, f1w, f1b, f2w, f2b, f3w, f3b,
                                            (float*)d_out);
}

// Round 6
// 4029.109 us; speedup vs baseline: 1.4898x; 1.4898x over previous
//
#include <hip/hip_runtime.h>

#define NNODE 50000
#define NEDGE 800000
#define NLAYER 4
#define BN_EPS 1e-5f

#define NH (NNODE*64)   // 3,200,000
#define NE (NEDGE*64)   // 51,200,000

typedef __attribute__((ext_vector_type(8))) short short8v;

__device__ __forceinline__ float sigf(float x){ return 1.0f/(1.0f+__expf(-x)); }

__device__ __forceinline__ float bf2f(unsigned short u){
  union { unsigned int i; float f; } c; c.i = ((unsigned int)u)<<16; return c.f;
}
__device__ __forceinline__ unsigned short f2bf(float f){
  union { float f; unsigned int i; } c; c.f = f;
  unsigned int r = c.i + 0x7FFFu + ((c.i>>16)&1u);   // RNE (finite values)
  return (unsigned short)(r>>16);
}

// ---------------------------------------------------------------- utility
__global__ void k_zero_i(int* __restrict__ p, int n){
  int i = blockIdx.x*256 + threadIdx.x;
  if(i<n) p[i]=0;
}
__global__ void k_zero_stats(float* __restrict__ stats){
  stats[threadIdx.x] = 0.f;   // one block of 256
}
__global__ void k_count(const int* __restrict__ ei, int* __restrict__ cnt){
  int i = blockIdx.x*256 + threadIdx.x;
  if(i<NEDGE) atomicAdd(&cnt[ei[i]], 1);   // ei[0][i] = dst
}
__global__ void k_inv(const int* __restrict__ cnt, float* __restrict__ invc){
  int i = blockIdx.x*256 + threadIdx.x;
  if(i<NNODE){ int c=cnt[i]; invc[i] = 1.0f/(float)(c<1?1:c); }
}

// single-block exclusive scan of cnt -> row_ptr (+cursor copy); row_ptr[NNODE]=total
__global__ void k_scan(const int* __restrict__ cnt, int* __restrict__ row_ptr,
                       int* __restrict__ cursor){
  __shared__ int buf[256];
  __shared__ int carry;
  const int tid = threadIdx.x;
  if(tid==0) carry=0;
  __syncthreads();
  for(int base=0; base<NNODE; base+=256){
    int i = base+tid;
    int v = (i<NNODE)? cnt[i] : 0;
    buf[tid]=v; __syncthreads();
    #pragma unroll
    for(int off=1; off<256; off<<=1){
      int t = (tid>=off)? buf[tid-off] : 0;
      __syncthreads();
      buf[tid]+=t;
      __syncthreads();
    }
    int excl = carry + buf[tid]-v;
    if(i<NNODE){ row_ptr[i]=excl; cursor[i]=excl; }
    __syncthreads();
    if(tid==0) carry += buf[255];
    __syncthreads();
  }
  if(tid==0) row_ptr[NNODE]=carry;
}

__global__ void k_fill(const int* __restrict__ ei, int* __restrict__ cursor,
                       int* __restrict__ csr_eid){
  int i = blockIdx.x*256 + threadIdx.x;
  if(i<NEDGE){
    int pos = atomicAdd(&cursor[ei[i]], 1);
    csr_eid[pos] = i;
  }
}

__global__ void k_init_h(const float* __restrict__ x, const float* __restrict__ w,
                         const float* __restrict__ b, float* __restrict__ h){
  int t = blockIdx.x*256 + threadIdx.x;
  if(t>=NH) return;
  int i=t>>6, j=t&63;
  float v = x[2*i]*w[j] + x[2*i+1]*w[64+j] + b[j];
  h[t] = fmaxf(v, 0.0f);
}

__global__ void k_init_e(const float* __restrict__ ea, const float* __restrict__ w,
                         const float* __restrict__ b, unsigned short* __restrict__ e){
  int t = blockIdx.x*256 + threadIdx.x;      // pair index
  if(t >= NE/2) return;
  int i = t>>5;
  int j = (t&31)<<1;
  float a = ea[i];
  float v0 = fmaxf(a*w[j]   + b[j],   0.f);
  float v1 = fmaxf(a*w[j+1] + b[j+1], 0.f);
  unsigned int pk = (unsigned int)f2bf(v0) | ((unsigned int)f2bf(v1)<<16);
  *reinterpret_cast<unsigned int*>(&e[2*t]) = pk;
}

// ------------------------------------------------------------ tile helpers
__device__ __forceinline__ void tile_gemm(const float (&At)[64][68], const float (&Ws)[64][68],
                                          int r0, int c0, float (&acc)[4][4]){
  #pragma unroll 4
  for(int k=0;k<64;++k){
    const float4 a = *reinterpret_cast<const float4*>(&At[k][r0]);
    const float4 b = *reinterpret_cast<const float4*>(&Ws[k][c0]);
    const float av[4]={a.x,a.y,a.z,a.w};
    const float bv[4]={b.x,b.y,b.z,b.w};
    #pragma unroll
    for(int ri=0;ri<4;++ri)
      #pragma unroll
      for(int ci=0;ci<4;++ci)
        acc[ri][ci] = fmaf(av[ri], bv[ci], acc[ri][ci]);
  }
}

__device__ __forceinline__ void stage_At_f32(float (&At)[64][68], const float* __restrict__ src,
                                             int row0, int rowmax, int tid){
  for(int it=0; it<4; ++it){
    int idx = tid + it*256;
    int r = idx>>4, c4=(idx&15)<<2;
    int gr = row0 + r;
    float4 v = make_float4(0.f,0.f,0.f,0.f);
    if(gr < rowmax) v = *reinterpret_cast<const float4*>(&src[(size_t)gr*64 + c4]);
    At[c4+0][r]=v.x; At[c4+1][r]=v.y; At[c4+2][r]=v.z; At[c4+3][r]=v.w;
  }
}

__device__ __forceinline__ void stage_At_bf16(float (&At)[64][68], const unsigned short* __restrict__ src,
                                              int row0, int tid){
  #pragma unroll
  for(int it=0; it<2; ++it){
    int idx = tid + it*256;          // 0..511
    int r = idx>>3, c8 = (idx&7)<<3;
    int gr = row0 + r;
    const short8v v = *reinterpret_cast<const short8v*>(&src[(size_t)gr*64 + c8]);
    #pragma unroll
    for(int j=0;j<8;++j) At[c8+j][r] = bf2f((unsigned short)v[j]);
  }
}

__device__ __forceinline__ void stage_W(float (&Ws)[64][68], const float* __restrict__ W, int tid){
  for(int it=0; it<4; ++it){
    int idx = tid + it*256;
    int k = idx>>4, c4=(idx&15)<<2;
    *reinterpret_cast<float4*>(&Ws[k][c4]) = *reinterpret_cast<const float4*>(&W[k*64+c4]);
  }
}

// ---------------------------------------------------------- node GEMMs (U,V,B,C)
__device__ __forceinline__ void node_one_mat(float (&At)[64][68], float (&Ws)[64][68],
    const float* __restrict__ W, const float* __restrict__ B, float* __restrict__ O,
    int row0, int tid){
  __syncthreads();
  stage_W(Ws, W, tid);
  __syncthreads();
  const int tx=tid&15, ty=tid>>4, r0=tx<<2, c0=ty<<2;
  float acc[4][4]={{0.f}};
  tile_gemm(At, Ws, r0, c0, acc);
  const float4 b4 = *reinterpret_cast<const float4*>(&B[c0]);
  const float bb[4]={b4.x,b4.y,b4.z,b4.w};
  #pragma unroll
  for(int ri=0;ri<4;++ri){
    int gr = row0 + r0 + ri;
    if(gr < NNODE){
      float4 o = make_float4(acc[ri][0]+bb[0], acc[ri][1]+bb[1],
                             acc[ri][2]+bb[2], acc[ri][3]+bb[3]);
      *reinterpret_cast<float4*>(&O[(size_t)gr*64 + c0]) = o;
    }
  }
}

__global__ __launch_bounds__(256) void k_node_gemm(
    const float* __restrict__ h,
    const float* __restrict__ Uw, const float* __restrict__ Ub,
    const float* __restrict__ Vw, const float* __restrict__ Vb,
    const float* __restrict__ Bw, const float* __restrict__ Bb,
    const float* __restrict__ Cw, const float* __restrict__ Cb,
    float* __restrict__ Uh, float* __restrict__ Vh,
    float* __restrict__ Bh, float* __restrict__ Ch)
{
  __shared__ float At[64][68];
  __shared__ float Ws[64][68];
  const int tid = threadIdx.x;
  const int row0 = blockIdx.x*64;
  stage_At_f32(At, h, row0, NNODE, tid);
  node_one_mat(At, Ws, Uw, Ub, Uh, row0, tid);
  node_one_mat(At, Ws, Vw, Vb, Vh, row0, tid);
  node_one_mat(At, Ws, Bw, Bb, Bh, row0, tid);
  node_one_mat(At, Ws, Cw, Cb, Ch, row0, tid);
}

// ---------------------------------------------------------- edge pass A
// t = e@Aw + Ab + Bh[dst] + Ch[src]; accumulate e-BN stats of t. NO scatter.
__global__ __launch_bounds__(256) void k_edge_A(
    const unsigned short* __restrict__ e,
    const float* __restrict__ Aw, const float* __restrict__ Ab,
    const float* __restrict__ Bh, const float* __restrict__ Ch,
    const int* __restrict__ ei,
    float* __restrict__ stats)
{
  __shared__ float At[64][68];
  __shared__ float Ws[64][68];
  __shared__ float red[128];
  const int tid=threadIdx.x;
  const int row0 = blockIdx.x*64;
  if(tid<128) red[tid]=0.f;
  stage_At_bf16(At, e, row0, tid);
  stage_W(Ws, Aw, tid);
  __syncthreads();
  const int tx=tid&15, ty=tid>>4, r0=tx<<2, c0=ty<<2;
  float acc[4][4]={{0.f}};
  tile_gemm(At, Ws, r0, c0, acc);

  int dstI[4], srcI[4];
  #pragma unroll
  for(int ri=0;ri<4;++ri){
    dstI[ri]=ei[row0+r0+ri];
    srcI[ri]=ei[NEDGE+row0+r0+ri];
  }
  const float4 ab4 = *reinterpret_cast<const float4*>(&Ab[c0]);
  const float ab[4]={ab4.x,ab4.y,ab4.z,ab4.w};

  float s1[4]={0.f,0.f,0.f,0.f}, s2[4]={0.f,0.f,0.f,0.f};
  #pragma unroll
  for(int ri=0;ri<4;++ri){
    const float4 bh4 = *reinterpret_cast<const float4*>(&Bh[(size_t)dstI[ri]*64 + c0]);
    const float4 ch4 = *reinterpret_cast<const float4*>(&Ch[(size_t)srcI[ri]*64 + c0]);
    const float bh[4]={bh4.x,bh4.y,bh4.z,bh4.w};
    const float ch[4]={ch4.x,ch4.y,ch4.z,ch4.w};
    #pragma unroll
    for(int ci=0;ci<4;++ci){
      float t = acc[ri][ci] + ab[ci] + bh[ci] + ch[ci];
      s1[ci]+=t; s2[ci]+=t*t;
    }
  }
  #pragma unroll
  for(int ci=0;ci<4;++ci){
    atomicAdd(&red[c0+ci],    s1[ci]);
    atomicAdd(&red[64+c0+ci], s2[ci]);
  }
  __syncthreads();
  if(tid<64){
    atomicAdd(&stats[tid],    red[tid]);
    atomicAdd(&stats[64+tid], red[64+tid]);
  }
}

// ---------------------------------------------------------- CSR aggregation + node finalize stats
// one wave (64 lanes) per node; lane = channel
// Uh[n] += invc[n] * sum_{edges->n} sigmoid(e[eid]) * Vh[src]; h-BN stats of result
__global__ __launch_bounds__(256) void k_agg(
    const unsigned short* __restrict__ e,
    const float* __restrict__ Vh,
    const int* __restrict__ ei,
    const int* __restrict__ row_ptr, const int* __restrict__ csr_eid,
    const float* __restrict__ invc,
    float* __restrict__ Uh, float* __restrict__ stats)
{
  __shared__ float red[128];
  const int tid=threadIdx.x;
  if(tid<128) red[tid]=0.f;
  __syncthreads();
  const int lane = tid&63;
  const int node = blockIdx.x*4 + (tid>>6);   // 4 waves/block, NNODE%4==0
  const int beg = row_ptr[node];
  const int end = row_ptr[node+1];
  float acc = 0.f;
  for(int p=beg; p<end; ++p){
    int eid = csr_eid[p];
    int src = ei[NEDGE+eid];
    float g = sigf(bf2f(e[(size_t)eid*64 + lane]));
    acc = fmaf(g, Vh[(size_t)src*64 + lane], acc);
  }
  size_t o = (size_t)node*64 + lane;
  float val = Uh[o] + acc*invc[node];
  Uh[o] = val;
  atomicAdd(&red[lane], val);
  atomicAdd(&red[64+lane], val*val);
  __syncthreads();
  if(tid<128) atomicAdd(&stats[128+tid], red[tid]);
}

__global__ void k_node_finB(const float* __restrict__ th, float* __restrict__ h,
                            const float* __restrict__ stats,
                            const float* __restrict__ hg, const float* __restrict__ hb){
  int t = blockIdx.x*256 + threadIdx.x;
  if(t>=NH) return;
  int j=t&63;
  const float invN = 1.0f/(float)NNODE;
  float mean = stats[128+j]*invN;
  float var  = stats[192+j]*invN - mean*mean;
  float rstd = rsqrtf(var + BN_EPS);
  float v = (th[t]-mean)*rstd*hg[j] + hb[j];
  h[t] += fmaxf(v, 0.0f);
}

// ---------------------------------------------------------- edge pass B
__global__ __launch_bounds__(256) void k_edge_B(
    unsigned short* __restrict__ e,
    const float* __restrict__ Aw, const float* __restrict__ Ab,
    const float* __restrict__ Bh, const float* __restrict__ Ch,
    const int* __restrict__ ei,
    const float* __restrict__ stats,
    const float* __restrict__ eg, const float* __restrict__ eb)
{
  __shared__ float At[64][68];
  __shared__ float Ws[64][68];
  const int tid=threadIdx.x;
  const int row0 = blockIdx.x*64;
  stage_At_bf16(At, e, row0, tid);
  stage_W(Ws, Aw, tid);
  __syncthreads();
  const int tx=tid&15, ty=tid>>4, r0=tx<<2, c0=ty<<2;
  float acc[4][4]={{0.f}};
  tile_gemm(At, Ws, r0, c0, acc);

  int dstI[4], srcI[4];
  #pragma unroll
  for(int ri=0;ri<4;++ri){
    dstI[ri]=ei[row0+r0+ri];
    srcI[ri]=ei[NEDGE+row0+r0+ri];
  }
  const float4 ab4 = *reinterpret_cast<const float4*>(&Ab[c0]);
  const float ab[4]={ab4.x,ab4.y,ab4.z,ab4.w};
  const float invE = 1.0f/(float)NEDGE;
  const float4 s14 = *reinterpret_cast<const float4*>(&stats[c0]);
  const float4 s24 = *reinterpret_cast<const float4*>(&stats[64+c0]);
  const float4 gg4 = *reinterpret_cast<const float4*>(&eg[c0]);
  const float4 bb4 = *reinterpret_cast<const float4*>(&eb[c0]);
  float mean[4], rstd[4], gg[4], bb[4];
  {
    const float s1v[4]={s14.x,s14.y,s14.z,s14.w};
    const float s2v[4]={s24.x,s24.y,s24.z,s24.w};
    const float ggv[4]={gg4.x,gg4.y,gg4.z,gg4.w};
    const float bbv[4]={bb4.x,bb4.y,bb4.z,bb4.w};
    #pragma unroll
    for(int ci=0;ci<4;++ci){
      mean[ci]=s1v[ci]*invE;
      float var = s2v[ci]*invE - mean[ci]*mean[ci];
      rstd[ci]=rsqrtf(var+BN_EPS);
      gg[ci]=ggv[ci]; bb[ci]=bbv[ci];
    }
  }
  float ein[4][4];
  #pragma unroll
  for(int ci=0;ci<4;++ci){
    const float4 q = *reinterpret_cast<const float4*>(&At[c0+ci][r0]);
    ein[0][ci]=q.x; ein[1][ci]=q.y; ein[2][ci]=q.z; ein[3][ci]=q.w;
  }
  #pragma unroll
  for(int ri=0;ri<4;++ri){
    const float4 bh4 = *reinterpret_cast<const float4*>(&Bh[(size_t)dstI[ri]*64 + c0]);
    const float4 ch4 = *reinterpret_cast<const float4*>(&Ch[(size_t)srcI[ri]*64 + c0]);
    const float bh[4]={bh4.x,bh4.y,bh4.z,bh4.w};
    const float ch[4]={ch4.x,ch4.y,ch4.z,ch4.w};
    unsigned int pk[2];
    #pragma unroll
    for(int p=0;p<2;++p){
      float o0, o1;
      {
        int ci=2*p;
        float t = acc[ri][ci] + ab[ci] + bh[ci] + ch[ci];
        float v = (t-mean[ci])*rstd[ci]*gg[ci] + bb[ci];
        o0 = ein[ri][ci] + fmaxf(v, 0.0f);
        ci=2*p+1;
        t = acc[ri][ci] + ab[ci] + bh[ci] + ch[ci];
        v = (t-mean[ci])*rstd[ci]*gg[ci] + bb[ci];
        o1 = ein[ri][ci] + fmaxf(v, 0.0f);
      }
      pk[p] = (unsigned int)f2bf(o0) | ((unsigned int)f2bf(o1)<<16);
    }
    *reinterpret_cast<uint2*>(&e[(size_t)(row0+r0+ri)*64 + c0]) = make_uint2(pk[0], pk[1]);
  }
}

// ---------------------------------------------------------- final MLP (fused)
__global__ __launch_bounds__(256) void k_mlp(
    const unsigned short* __restrict__ e,
    const float* __restrict__ f1w, const float* __restrict__ f1b,
    const float* __restrict__ f2w, const float* __restrict__ f2b,
    const float* __restrict__ f3w, const float* __restrict__ f3b,
    float* __restrict__ out)
{
  __shared__ float At[64][68];
  __shared__ float Ws[64][68];
  __shared__ float ored[64];
  const int tid=threadIdx.x;
  const int row0 = blockIdx.x*64;
  if(tid<64) ored[tid]=0.f;
  stage_At_bf16(At, e, row0, tid);
  stage_W(Ws, f1w, tid);
  __syncthreads();
  const int tx=tid&15, ty=tid>>4, r0=tx<<2, c0=ty<<2;
  float acc[4][4]={{0.f}};
  tile_gemm(At, Ws, r0, c0, acc);
  const float4 b14 = *reinterpret_cast<const float4*>(&f1b[c0]);
  const float b1[4]={b14.x,b14.y,b14.z,b14.w};
  float z1[4][4];
  #pragma unroll
  for(int ri=0;ri<4;++ri)
    #pragma unroll
    for(int ci=0;ci<4;++ci){
      float v = acc[ri][ci]+b1[ci];
      z1[ri][ci] = v*sigf(v);
    }
  __syncthreads();
  #pragma unroll
  for(int ri=0;ri<4;++ri)
    #pragma unroll
    for(int ci=0;ci<4;++ci)
      At[c0+ci][r0+ri] = z1[ri][ci];
  stage_W(Ws, f2w, tid);
  __syncthreads();
  float acc2[4][4]={{0.f}};
  tile_gemm(At, Ws, r0, c0, acc2);
  const float4 b24 = *reinterpret_cast<const float4*>(&f2b[c0]);
  const float b2[4]={b24.x,b24.y,b24.z,b24.w};
  const float4 w34 = *reinterpret_cast<const float4*>(&f3w[c0]);
  const float w3[4]={w34.x,w34.y,w34.z,w34.w};
  float part[4]={0.f,0.f,0.f,0.f};
  #pragma unroll
  for(int ri=0;ri<4;++ri)
    #pragma unroll
    for(int ci=0;ci<4;++ci){
      float v = acc2[ri][ci]+b2[ci];
      float z = v*sigf(v);
      part[ri] += z*w3[ci];
    }
  #pragma unroll
  for(int ri=0;ri<4;++ri) atomicAdd(&ored[r0+ri], part[ri]);
  __syncthreads();
  if(tid<64) out[row0+tid] = sigf(ored[tid] + f3b[0]);
}

// ---------------------------------------------------------------- launch
extern "C" void kernel_launch(void* const* d_in, const int* in_sizes, int n_in,
                              void* d_out, int out_size, void* d_ws, size_t ws_size,
                              hipStream_t stream){
  const float* x    = (const float*)d_in[0];
  const float* ea   = (const float*)d_in[1];
  const int*   ei   = (const int*)  d_in[2];
  const float* hp_w = (const float*)d_in[3];
  const float* hp_b = (const float*)d_in[4];
  const float* ep_w = (const float*)d_in[5];
  const float* ep_b = (const float*)d_in[6];
  const float* Uw   = (const float*)d_in[7];
  const float* Ub   = (const float*)d_in[8];
  const float* Vw   = (const float*)d_in[9];
  const float* Vb   = (const float*)d_in[10];
  const float* Aw   = (const float*)d_in[11];
  const float* Ab   = (const float*)d_in[12];
  const float* Bw   = (const float*)d_in[13];
  const float* Bb   = (const float*)d_in[14];
  const float* Cw   = (const float*)d_in[15];
  const float* Cb   = (const float*)d_in[16];
  const float* hg   = (const float*)d_in[17];
  const float* hb   = (const float*)d_in[18];
  const float* eg   = (const float*)d_in[19];
  const float* eb   = (const float*)d_in[20];
  const float* f1w  = (const float*)d_in[21];
  const float* f1b  = (const float*)d_in[22];
  const float* f2w  = (const float*)d_in[23];
  const float* f2b  = (const float*)d_in[24];
  const float* f3w  = (const float*)d_in[25];
  const float* f3b  = (const float*)d_in[26];

  // ws layout: e(bf16 NE) | h,Uh,Vh,Bh,Ch (f32 NH each) | stats(256) | cnt | invc | row_ptr | cursor | csr_eid
  char* base = (char*)d_ws;
  unsigned short* e = (unsigned short*)base;            // 102.4 MB
  float* h     = (float*)(base + (size_t)NE*2);
  float* Uh    = h  + (size_t)NH;
  float* Vh    = h  + 2ull*NH;
  float* Bh    = h  + 3ull*NH;
  float* Ch    = h  + 4ull*NH;
  float* stats = h  + 5ull*NH;            // 256 floats
  int*   cnt     = (int*)(stats + 256);   // NNODE
  float* invc    = (float*)(cnt + NNODE); // NNODE
  int*   row_ptr = (int*)(invc + NNODE);  // NNODE+1
  int*   cursor  = row_ptr + NNODE + 1;   // NNODE
  int*   csr_eid = cursor + NNODE;        // NEDGE
  // total ≈ 170.4 MB

  dim3 blk(256);
  k_zero_i<<<dim3((NNODE+255)/256), blk, 0, stream>>>(cnt, NNODE);
  k_count <<<dim3((NEDGE+255)/256), blk, 0, stream>>>(ei, cnt);
  k_inv   <<<dim3((NNODE+255)/256), blk, 0, stream>>>(cnt, invc);
  k_scan  <<<dim3(1), blk, 0, stream>>>(cnt, row_ptr, cursor);
  k_fill  <<<dim3((NEDGE+255)/256), blk, 0, stream>>>(ei, cursor, csr_eid);
  k_init_h<<<dim3((NH+255)/256), blk, 0, stream>>>(x, hp_w, hp_b, h);
  k_init_e<<<dim3((NE/2+255)/256), blk, 0, stream>>>(ea, ep_w, ep_b, e);

  for(int l=0;l<NLAYER;++l){
    k_zero_stats<<<dim3(1), blk, 0, stream>>>(stats);
    k_node_gemm<<<dim3((NNODE+63)/64), blk, 0, stream>>>(h,
        Uw+l*4096, Ub+l*64, Vw+l*4096, Vb+l*64,
        Bw+l*4096, Bb+l*64, Cw+l*4096, Cb+l*64,
        Uh, Vh, Bh, Ch);
    k_edge_A<<<dim3(NEDGE/64), blk, 0, stream>>>(e, Aw+l*4096, Ab+l*64,
        Bh, Ch, ei, stats);
    k_agg<<<dim3(NNODE/4), blk, 0, stream>>>(e, Vh, ei, row_ptr, csr_eid,
        invc, Uh, stats);
    k_node_finB<<<dim3(NH/256), blk, 0, stream>>>(Uh, h, stats, hg+l*64, hb+l*64);
    k_edge_B<<<dim3(NEDGE/64), blk, 0, stream>>>(e, Aw+l*4096, Ab+l*64,
        Bh, Ch, ei, stats, eg+l*64, eb+l*64);
  }
  k_mlp<<<dim3(NEDGE/64), blk, 0, stream>>>(e, f1w, f1b, f2w, f2b, f3w, f3b,
                                            (float*)d_out);
}